// Round 2
// baseline (198.285 us; speedup 1.0000x reference)
//
#include <hip/hip_runtime.h>
#include <math.h>

// YOLOv3 decode: x[N=16, A=3, C=85, H=76, W=76] f32 -> out[48, 5776, 85] f32
// Per (n,a) slice this is an 85 x 5776 transpose with per-channel elementwise math.
// Memory-bound: 94.3 MB in + 94.3 MB out, roofline ~30 us at 6.3 TB/s.

#define NCH     85
#define SPATIAL 5776      // 76*76, contiguous within each channel plane
#define GWID    76
#define TS      128       // spatial tile per block
#define TSP     129       // padded LDS stride (129 % 32 == 1 -> conflict-free)
#define NTILES  46        // ceil(5776/128)

__device__ __forceinline__ float fast_sigmoid(float v) {
    return __builtin_amdgcn_rcpf(1.0f + __expf(-v));
}

__global__ __launch_bounds__(256) void yolo_decode(
    const float* __restrict__ x,
    const float* __restrict__ anchors,
    float* __restrict__ out)
{
    __shared__ float tile[NCH * TSP];   // ~43.9 KB -> 3 blocks/CU

    const int na  = blockIdx.y;         // 0..47  (n*3 + a)
    const int a   = na % 3;
    const int s0  = blockIdx.x * TS;
    const int rem = min(TS, SPATIAL - s0);
    const int t   = threadIdx.x;

    const float* in_base = x + (size_t)na * NCH * SPATIAL + s0;

    // ---- load phase: coalesced along spatial ----
    if (rem == TS) {
        // float4 path: 85 * 32 = 2720 vector loads
        for (int g = t; g < NCH * (TS / 4); g += 256) {
            const int c  = g >> 5;          // g / 32
            const int s4 = (g & 31) << 2;   // (g % 32) * 4
            const float4 v = *reinterpret_cast<const float4*>(in_base + c * SPATIAL + s4);
            float* dst = &tile[c * TSP + s4];
            dst[0] = v.x; dst[1] = v.y; dst[2] = v.z; dst[3] = v.w;
        }
    } else {
        for (int g = t; g < NCH * rem; g += 256) {
            const int c = g / rem;
            const int s = g - c * rem;
            tile[c * TSP + s] = in_base[c * SPATIAL + s];
        }
    }
    __syncthreads();

    const float aw = anchors[a * 2 + 0] * (1.0f / 608.0f);
    const float ah = anchors[a * 2 + 1] * (1.0f / 608.0f);

    // ---- store phase: output chunk for this tile is fully contiguous ----
    // chunk = out[(na*5776 + s0)*85 ... +85*rem), 16B-aligned, length % 16B == 0
    float* out_base = out + ((size_t)na * SPATIAL + s0) * NCH;
    const int nv4 = (NCH * rem) >> 2;   // 85*128/4 = 2720 (or 85*16/4 = 340 tail)

    for (int v = t; v < nv4; v += 256) {
        const int fb = v << 2;
        float4 o;
        float* op = &o.x;
        #pragma unroll
        for (int j = 0; j < 4; ++j) {
            const int f = fb + j;
            const int s = f / NCH;          // local spatial in tile
            const int c = f - s * NCH;      // channel
            const float val = tile[c * TSP + s];
            const int sg = s0 + s;          // global spatial = h*76 + w
            float r;
            if (c == 0) {
                r = (fast_sigmoid(val) + (float)(sg % GWID)) * (1.0f / GWID);
            } else if (c == 1) {
                r = (fast_sigmoid(val) + (float)(sg / GWID)) * (1.0f / GWID);
            } else if (c == 2) {
                r = __expf(val) * aw;
            } else if (c == 3) {
                r = __expf(val) * ah;
            } else {
                r = fast_sigmoid(val);
            }
            op[j] = r;
        }
        *reinterpret_cast<float4*>(out_base + fb) = o;
    }
}

extern "C" void kernel_launch(void* const* d_in, const int* in_sizes, int n_in,
                              void* d_out, int out_size, void* d_ws, size_t ws_size,
                              hipStream_t stream) {
    const float* x       = (const float*)d_in[0];
    const float* anchors = (const float*)d_in[1];
    float* out           = (float*)d_out;

    dim3 grid(NTILES, 48);   // 46 spatial tiles x (16 batch * 3 anchors)
    yolo_decode<<<grid, 256, 0, stream>>>(x, anchors, out);
}

// Round 3
// 170.869 us; speedup vs baseline: 1.1605x; 1.1605x over previous
//
#include <hip/hip_runtime.h>
#include <math.h>

// YOLOv3 decode: x[16, 3, 85, 76, 76] f32 -> out[48, 5776, 85] f32.
// Per (n,a) slice: 85 x 5776 transpose + cheap per-channel math.
// Strategy: LDS tile holds the OUTPUT layout (f = s_local*85 + c).
//   - math applied at LDS-write time (c uniform per lane, branch mostly uniform)
//   - ds_write_b32 scatter has 2-way banking (free); ds_read_b128 is linear
//   - TS=64 -> 21.76 KB LDS -> 7 blocks/CU -> 28 waves/CU
// Memory-bound floor: ~147 MB HBM traffic / 6.3 TB/s ~ 23 us.

#define NCH     85
#define SPATIAL 5776      // 76*76
#define GWID    76
#define TS      64        // spatial tile per block
#define NTILES  91        // 90 full tiles + 1 tail of 16

__device__ __forceinline__ float fast_sigmoid(float v) {
    return __builtin_amdgcn_rcpf(1.0f + __expf(-v));
}

__global__ __launch_bounds__(256) void yolo_decode(
    const float* __restrict__ x,
    const float* __restrict__ anchors,
    float* __restrict__ out)
{
    __shared__ __align__(16) float tile[NCH * TS];   // 21760 B, output-linear

    const int na  = blockIdx.y;          // n*3 + a
    const int a   = na % 3;
    const int s0  = blockIdx.x * TS;
    const int rem = (s0 + TS <= SPATIAL) ? TS : (SPATIAL - s0);   // 64 or 16
    const int t   = threadIdx.x;

    const float aw = anchors[a * 2 + 0] * (1.0f / 608.0f);
    const float ah = anchors[a * 2 + 1] * (1.0f / 608.0f);

    const float* in_base = x + (size_t)na * NCH * SPATIAL + s0;

    // ---- phase 1: coalesced float4 loads along spatial; math; scatter to LDS ----
    // lane mapping: c = idx>>4, k = idx&15 (full tile). 16 lanes per channel
    // cover a 256B contiguous global segment; LDS banks land 2-way (free).
    #define PROCESS(cc, sl4)                                                     \
        do {                                                                     \
            const int c  = (cc);                                                 \
            const int sl = (sl4);                                                \
            const float4 v = *reinterpret_cast<const float4*>(                   \
                in_base + c * SPATIAL + sl);                                     \
            float vv[4] = {v.x, v.y, v.z, v.w};                                  \
            if (c >= 4) {                /* conf + class probs: sigmoid */       \
                _Pragma("unroll")                                                \
                for (int jj = 0; jj < 4; ++jj)                                   \
                    tile[(sl + jj) * NCH + c] = fast_sigmoid(vv[jj]);            \
            } else if (c == 0) {                                                 \
                _Pragma("unroll")                                                \
                for (int jj = 0; jj < 4; ++jj) {                                 \
                    const int sg = s0 + sl + jj;                                 \
                    tile[(sl + jj) * NCH + c] =                                  \
                        (fast_sigmoid(vv[jj]) + (float)(sg % GWID)) *            \
                        (1.0f / GWID);                                           \
                }                                                                \
            } else if (c == 1) {                                                 \
                _Pragma("unroll")                                                \
                for (int jj = 0; jj < 4; ++jj) {                                 \
                    const int sg = s0 + sl + jj;                                 \
                    tile[(sl + jj) * NCH + c] =                                  \
                        (fast_sigmoid(vv[jj]) + (float)(sg / GWID)) *            \
                        (1.0f / GWID);                                           \
                }                                                                \
            } else if (c == 2) {                                                 \
                _Pragma("unroll")                                                \
                for (int jj = 0; jj < 4; ++jj)                                   \
                    tile[(sl + jj) * NCH + c] = __expf(vv[jj]) * aw;             \
            } else {                     /* c == 3 */                            \
                _Pragma("unroll")                                                \
                for (int jj = 0; jj < 4; ++jj)                                   \
                    tile[(sl + jj) * NCH + c] = __expf(vv[jj]) * ah;             \
            }                                                                    \
        } while (0)

    if (rem == TS) {
        for (int idx = t; idx < NCH * (TS / 4); idx += 256)      // 1360
            PROCESS(idx >> 4, (idx & 15) << 2);
    } else {
        // tail tile: rem == 16
        for (int idx = t; idx < NCH * 4; idx += 256)             // 340
            PROCESS(idx >> 2, (idx & 3) << 2);
    }
    #undef PROCESS

    __syncthreads();

    // ---- phase 2: LDS is already output-layout; straight b128 copy out ----
    float* out_base = out + ((size_t)na * SPATIAL + s0) * NCH;   // 16B aligned
    const int nv4 = (NCH * rem) >> 2;    // 1360 (full) or 340 (tail)
    for (int v = t; v < nv4; v += 256) {
        const float4 o = *reinterpret_cast<const float4*>(&tile[v << 2]);
        *reinterpret_cast<float4*>(out_base + (v << 2)) = o;
    }
}

extern "C" void kernel_launch(void* const* d_in, const int* in_sizes, int n_in,
                              void* d_out, int out_size, void* d_ws, size_t ws_size,
                              hipStream_t stream) {
    const float* x       = (const float*)d_in[0];
    const float* anchors = (const float*)d_in[1];
    float* out           = (float*)d_out;

    dim3 grid(NTILES, 48);   // 91 spatial tiles x (16 batch * 3 anchors)
    yolo_decode<<<grid, 256, 0, stream>>>(x, anchors, out);
}

// Round 4
// 168.691 us; speedup vs baseline: 1.1754x; 1.0129x over previous
//
#include <hip/hip_runtime.h>
#include <math.h>

// YOLOv3 decode: x[16, 3, 85, 76, 76] f32 -> out[48, 5776, 85] f32.
// Per (n,a) slice: 85 x 5776 transpose + cheap per-channel math.
// LDS tile holds OUTPUT layout; math at LDS-write time.
// This round: hand-unrolled phases (5 const-trip iters + 80-thread tail) so
// each thread issues 5-6 independent global loads before any vmcnt wait.
// Memory floor: ~153 MB HBM traffic / 6.3 TB/s ~ 24 us.

#define NCH     85
#define SPATIAL 5776      // 76*76
#define GWID    76
#define TS      64        // spatial tile per block
#define NTILES  91        // 90 full tiles + 1 tail of 16

__device__ __forceinline__ float fast_sigmoid(float v) {
    return __builtin_amdgcn_rcpf(1.0f + __expf(-v));
}

__device__ __forceinline__ void process4(float* __restrict__ tile,
                                         int c, int sl, int s0,
                                         float4 v, float aw, float ah) {
    float vv[4] = {v.x, v.y, v.z, v.w};
    if (c >= 4) {                      // conf + class probs: sigmoid
        #pragma unroll
        for (int jj = 0; jj < 4; ++jj)
            tile[(sl + jj) * NCH + c] = fast_sigmoid(vv[jj]);
    } else if (c == 0) {
        #pragma unroll
        for (int jj = 0; jj < 4; ++jj) {
            const int sg = s0 + sl + jj;
            tile[(sl + jj) * NCH + c] =
                (fast_sigmoid(vv[jj]) + (float)(sg % GWID)) * (1.0f / GWID);
        }
    } else if (c == 1) {
        #pragma unroll
        for (int jj = 0; jj < 4; ++jj) {
            const int sg = s0 + sl + jj;
            tile[(sl + jj) * NCH + c] =
                (fast_sigmoid(vv[jj]) + (float)(sg / GWID)) * (1.0f / GWID);
        }
    } else if (c == 2) {
        #pragma unroll
        for (int jj = 0; jj < 4; ++jj)
            tile[(sl + jj) * NCH + c] = __expf(vv[jj]) * aw;
    } else {                           // c == 3
        #pragma unroll
        for (int jj = 0; jj < 4; ++jj)
            tile[(sl + jj) * NCH + c] = __expf(vv[jj]) * ah;
    }
}

__global__ __launch_bounds__(256) void yolo_decode(
    const float* __restrict__ x,
    const float* __restrict__ anchors,
    float* __restrict__ out)
{
    __shared__ __align__(16) float tile[NCH * TS];   // 21760 B -> 7 blocks/CU

    const int na  = blockIdx.y;          // n*3 + a
    const int a   = na % 3;
    const int s0  = blockIdx.x * TS;
    const int t   = threadIdx.x;

    const float aw = anchors[a * 2 + 0] * (1.0f / 608.0f);
    const float ah = anchors[a * 2 + 1] * (1.0f / 608.0f);

    const float* in_base = x + (size_t)na * NCH * SPATIAL + s0;
    float* out_base = out + ((size_t)na * SPATIAL + s0) * NCH;   // 16B aligned

    if (s0 + TS <= SPATIAL) {
        // ================= full tile: 85*16 = 1360 float4 = 5*256 + 80 ======
        // idx = t + 256*i  ->  c = (t>>4) + 16*i,  sl = (t&15)*4 (invariant)
        const int sl    = (t & 15) << 2;
        const int cbase = t >> 4;
        const bool extra = (t < 80);

        // ---- phase 1: issue ALL loads first (5 + tail), then math+scatter --
        const float* p = in_base + cbase * SPATIAL + sl;
        float4 v0 = *reinterpret_cast<const float4*>(p);
        float4 v1 = *reinterpret_cast<const float4*>(p + 16 * SPATIAL);
        float4 v2 = *reinterpret_cast<const float4*>(p + 32 * SPATIAL);
        float4 v3 = *reinterpret_cast<const float4*>(p + 48 * SPATIAL);
        float4 v4 = *reinterpret_cast<const float4*>(p + 64 * SPATIAL);
        float4 vt;
        int ct = 80 + cbase;             // c for tail (t<80): 80..84
        if (extra)
            vt = *reinterpret_cast<const float4*>(in_base + ct * SPATIAL + sl);

        process4(tile, cbase +  0, sl, s0, v0, aw, ah);
        process4(tile, cbase + 16, sl, s0, v1, aw, ah);
        process4(tile, cbase + 32, sl, s0, v2, aw, ah);
        process4(tile, cbase + 48, sl, s0, v3, aw, ah);
        process4(tile, cbase + 64, sl, s0, v4, aw, ah);
        if (extra)
            process4(tile, ct, sl, s0, vt, aw, ah);

        __syncthreads();

        // ---- phase 2: linear b128 reads + contiguous dwordx4 stores --------
        const int fb = t << 2;           // float offset; +1024 per iter
        float4 o0 = *reinterpret_cast<const float4*>(&tile[fb]);
        float4 o1 = *reinterpret_cast<const float4*>(&tile[fb + 1024]);
        float4 o2 = *reinterpret_cast<const float4*>(&tile[fb + 2048]);
        float4 o3 = *reinterpret_cast<const float4*>(&tile[fb + 3072]);
        float4 o4 = *reinterpret_cast<const float4*>(&tile[fb + 4096]);
        *reinterpret_cast<float4*>(out_base + fb)        = o0;
        *reinterpret_cast<float4*>(out_base + fb + 1024) = o1;
        *reinterpret_cast<float4*>(out_base + fb + 2048) = o2;
        *reinterpret_cast<float4*>(out_base + fb + 3072) = o3;
        *reinterpret_cast<float4*>(out_base + fb + 4096) = o4;
        if (extra) {
            const int fbt = 5120 + (t << 2);
            float4 ot = *reinterpret_cast<const float4*>(&tile[fbt]);
            *reinterpret_cast<float4*>(out_base + fbt) = ot;
        }
    } else {
        // ================= tail tile (rem = 16): generic path, 48 blocks ====
        const int rem = SPATIAL - s0;    // 16
        for (int idx = t; idx < NCH * (rem / 4); idx += 256) {
            const int c  = idx / (rem / 4);
            const int sl = (idx - c * (rem / 4)) << 2;
            const float4 v = *reinterpret_cast<const float4*>(
                in_base + c * SPATIAL + sl);
            process4(tile, c, sl, s0, v, aw, ah);
        }
        __syncthreads();
        const int nv4 = (NCH * rem) >> 2;   // 340
        for (int v = t; v < nv4; v += 256) {
            const float4 o = *reinterpret_cast<const float4*>(&tile[v << 2]);
            *reinterpret_cast<float4*>(out_base + (v << 2)) = o;
        }
    }
}

extern "C" void kernel_launch(void* const* d_in, const int* in_sizes, int n_in,
                              void* d_out, int out_size, void* d_ws, size_t ws_size,
                              hipStream_t stream) {
    const float* x       = (const float*)d_in[0];
    const float* anchors = (const float*)d_in[1];
    float* out           = (float*)d_out;

    dim3 grid(NTILES, 48);   // 91 spatial tiles x (16 batch * 3 anchors)
    yolo_decode<<<grid, 256, 0, stream>>>(x, anchors, out);
}